// Round 3
// baseline (558.249 us; speedup 1.0000x reference)
//
#include <hip/hip_runtime.h>
#include <hip/hip_bf16.h>
#include <stdint.h>

typedef unsigned short u16;
typedef unsigned int u32;
typedef __bf16 bf16x8 __attribute__((ext_vector_type(8)));
typedef float f32x4 __attribute__((ext_vector_type(4)));
typedef u16 u16x4 __attribute__((ext_vector_type(4)));

typedef const __attribute__((address_space(1))) void* gas_ptr;
typedef __attribute__((address_space(3))) void* las_ptr;

#define M_DIM 8192
#define K_DIM 4096
#define N_DIM 4096

__device__ __forceinline__ u16 f32_to_bf16_rne(float f) {
    u32 u = __float_as_uint(f);
    u += 0x7FFFu + ((u >> 16) & 1u);
    return (u16)(u >> 16);
}

// ---- 1) max|W| reduction -> ws[0] as float bits (atomicMax on uint works for non-negative floats)
__global__ void maxabs_kernel(const float* __restrict__ W, u32* __restrict__ out, int n4) {
    int idx = blockIdx.x * blockDim.x + threadIdx.x;
    int stride = gridDim.x * blockDim.x;
    const float4* W4 = (const float4*)W;
    float m = 0.0f;
    for (int i = idx; i < n4; i += stride) {
        float4 v = W4[i];
        m = fmaxf(m, fmaxf(fmaxf(fabsf(v.x), fabsf(v.y)), fmaxf(fabsf(v.z), fabsf(v.w))));
    }
#pragma unroll
    for (int off = 32; off > 0; off >>= 1)
        m = fmaxf(m, __shfl_down(m, off));
    if ((threadIdx.x & 63) == 0)
        atomicMax(out, __float_as_uint(m));
}

// ---- 2) quantize W (K x N, fp32) -> bf16 W^T (N x K). w_q integer in [-127,127]: exact in bf16.
__global__ void quant_transpose_kernel(const float* __restrict__ W, u16* __restrict__ Wt,
                                       const u32* __restrict__ mb) {
    __shared__ u16 tile[32][33];
    const float s_inv = 128.0f / __uint_as_float(*mb);  // 1/s_w, s_w = 2*max/256 = max/128
    int n = blockIdx.x * 32 + threadIdx.x;
#pragma unroll
    for (int r = threadIdx.y; r < 32; r += 8) {
        int k = blockIdx.y * 32 + r;
        float q = rintf(W[(size_t)k * N_DIM + n] * s_inv);  // rintf = round-half-even (matches jnp.round)
        q = fminf(fmaxf(q, -127.0f), 127.0f);
        tile[threadIdx.x][r] = (u16)(__float_as_uint(q) >> 16);  // truncation exact for small ints
    }
    __syncthreads();
    int k_out = blockIdx.y * 32 + threadIdx.x;
#pragma unroll
    for (int r = threadIdx.y; r < 32; r += 8) {
        int n_out = blockIdx.x * 32 + r;
        Wt[(size_t)n_out * K_DIM + k_out] = tile[r][threadIdx.x];
    }
}

// ---- 3) cast xb fp32 -> bf16 (RNE)
__global__ void cast_bf16_kernel(const float* __restrict__ x, u16* __restrict__ y, int n4) {
    int idx = blockIdx.x * blockDim.x + threadIdx.x;
    int stride = gridDim.x * blockDim.x;
    const float4* x4 = (const float4*)x;
    u16x4* y4 = (u16x4*)y;
    for (int i = idx; i < n4; i += stride) {
        float4 v = x4[i];
        u16x4 o;
        o.x = f32_to_bf16_rne(v.x);
        o.y = f32_to_bf16_rne(v.y);
        o.z = f32_to_bf16_rne(v.z);
        o.w = f32_to_bf16_rne(v.w);
        y4[i] = o;
    }
}

// ---- 4) GEMM: out[M][N] = s_w * (A[M][K] @ Bt[N][K]^T) + bias
// 256x256 tile, BK=64, 8 waves (2M x 4N). 2-barrier-per-K-tile schedule: ds_reads issued in
// groups with compiler-precise counted lgkm waits so the LDS pipe (1536 cy read + 512 cy write
// per K-tile per CU) runs UNDER the MFMA shadow (2060 cy) instead of serialized with it.
// Barriers only guard staging-write visibility (vmcnt(N)+barrier pairs, never drained to 0
// in the main loop). LDS (dynamic, 128 KiB): buf0/1 = A dbuf (256x64 bf16), buf2/3 = B dbuf.
// XOR swizzle: phys_byte = row*128 + (col_byte ^ ((row&7)<<4)); inverse-swizzled global source
// (global_load_lds writes linearly) + swizzled ds_read addresses. Bank conflicts measured 0.

#define BAR() __builtin_amdgcn_s_barrier()
#define SCB() __builtin_amdgcn_sched_barrier(0)
#define VMC(N) asm volatile("s_waitcnt vmcnt(" #N ")" ::: "memory")
#define PRIO1() __builtin_amdgcn_s_setprio(1)
#define PRIO0() __builtin_amdgcn_s_setprio(0)

// ds-read A fragments for m-half MH: a[i][ks], rows wm*128 + MH*64 + i*16 + l15
#define DS_A(ABASE, MH)                                            \
    do {                                                           \
        _Pragma("unroll") for (int i_ = 0; i_ < 4; ++i_) {         \
            const char* p_ = (ABASE) + ((MH)*64 + i_ * 16) * 128;  \
            a[i_][0] = *(const bf16x8*)(p_ + ck0);                 \
            a[i_][1] = *(const bf16x8*)(p_ + ck1);                 \
        }                                                          \
    } while (0)

// ds-read B fragments for n-half NH: b[NH*2+j][ks], rows wn*64 + NH*32 + j*16 + l15
#define DS_B(BBASE, NH)                                            \
    do {                                                           \
        _Pragma("unroll") for (int j_ = 0; j_ < 2; ++j_) {         \
            const char* p_ = (BBASE) + ((NH)*32 + j_ * 16) * 128;  \
            b[(NH)*2 + j_][0] = *(const bf16x8*)(p_ + ck0);        \
            b[(NH)*2 + j_][1] = *(const bf16x8*)(p_ + ck1);        \
        }                                                          \
    } while (0)

// 16 MFMAs: one C-quadrant (MH, NH) over full K=64 of the current tile
#define MM(MH, NH)                                                                            \
    do {                                                                                      \
        _Pragma("unroll") for (int i_ = 0; i_ < 4; ++i_) {                                    \
            _Pragma("unroll") for (int j_ = 0; j_ < 2; ++j_) {                                \
                f32x4& c_ = acc[(MH)*4 + i_][(NH)*2 + j_];                                    \
                c_ = __builtin_amdgcn_mfma_f32_16x16x32_bf16(a[i_][0], b[(NH)*2 + j_][0], c_, \
                                                             0, 0, 0);                        \
                c_ = __builtin_amdgcn_mfma_f32_16x16x32_bf16(a[i_][1], b[(NH)*2 + j_][1], c_, \
                                                             0, 0, 0);                        \
            }                                                                                 \
        }                                                                                     \
    } while (0)

// stage A half-tile HALF of k-tile T into buffer BUF (2 x global_load_lds; 16 KB total/block)
// HALF 0 -> rows {0-63, 128-191}; HALF 1 -> rows {64-127, 192-255}
#define STAGE_A(BUF, T, HALF)                                                                 \
    do {                                                                                      \
        const int r0_ = wave * 8 + (HALF)*64;                                                 \
        const u16* s_ = Ag + (size_t)r0_ * K_DIM + (T)*64;                                    \
        __builtin_amdgcn_global_load_lds((gas_ptr)s_, (las_ptr)&lds[BUF][r0_ * 64], 16, 0,    \
                                         0);                                                  \
        __builtin_amdgcn_global_load_lds((gas_ptr)(s_ + (size_t)128 * K_DIM),                 \
                                         (las_ptr)&lds[BUF][(r0_ + 128) * 64], 16, 0, 0);     \
    } while (0)

// stage B half-tile: HALF 0 -> rows {wn*64+0..31 for all wn}; HALF 1 -> +32
#define STAGE_B(BUF, T, HALF)                                                                  \
    do {                                                                                       \
        const int r0_ = bw + (HALF)*32;                                                        \
        const u16* s_ = Bg + (size_t)r0_ * K_DIM + (T)*64;                                     \
        __builtin_amdgcn_global_load_lds((gas_ptr)s_, (las_ptr)&lds[2 + (BUF)][r0_ * 64], 16,  \
                                         0, 0);                                                \
        __builtin_amdgcn_global_load_lds((gas_ptr)(s_ + (size_t)128 * K_DIM),                  \
                                         (las_ptr)&lds[2 + (BUF)][(r0_ + 128) * 64], 16, 0,    \
                                         0);                                                   \
    } while (0)

// One K-tile, 2 barriers. Read buffer = ABASE/BBASE; stage k-tile TS into buffer OBUF.
// Per-wave vmcnt FIFO (6-load group {A0,B0,B1}, then 2-load {A1} per tile):
//   tile start: outstanding = T.{A0,B0,B1}(6) + T.A1(2) -> VMC(2) waits the 6-group.
//   mid-tile:   outstanding = T.A1(2) + (T+1).{A0,B0,B1}(6) -> VMC(6) waits T.A1.
// VMC+BAR pairs make per-wave waits workgroup-wide. Staging targets in OBUF were last
// read one K-tile earlier (reads complete before the preceding barrier) -> no WAR race.
// First-half MFMA clusters (MM(0,0), MM(0,1)) consume only A0+B0/B1; second half overwrites
// a[] with A1 for MM(1,0)/MM(1,1); b[0..3] stays live across the mid barrier.
#define KTILE(ABASE, BBASE, OBUF, TS)  \
    do {                               \
        VMC(2);                        \
        BAR();                         \
        SCB();                         \
        STAGE_A(OBUF, TS, 0);          \
        STAGE_B(OBUF, TS, 0);          \
        STAGE_B(OBUF, TS, 1);          \
        DS_A(ABASE, 0);                \
        DS_B(BBASE, 0);                \
        DS_B(BBASE, 1);                \
        SCB();                         \
        PRIO1();                       \
        MM(0, 0);                      \
        MM(0, 1);                      \
        PRIO0();                       \
        VMC(6);                        \
        BAR();                         \
        SCB();                         \
        STAGE_A(OBUF, TS, 1);          \
        DS_A(ABASE, 1);                \
        SCB();                         \
        PRIO1();                       \
        MM(1, 0);                      \
        MM(1, 1);                      \
        PRIO0();                       \
    } while (0)

__global__ __launch_bounds__(512, 2) void gemm_kernel(const u16* __restrict__ A,
                                                      const u16* __restrict__ Bt,
                                                      const float* __restrict__ bias,
                                                      const u32* __restrict__ mb,
                                                      float* __restrict__ out) {
    extern __shared__ u16 lds_raw[];  // 128 KiB dynamic: A buf0, A buf1, B buf0, B buf1
    u16(*lds)[256 * 64] = reinterpret_cast<u16(*)[256 * 64]>(lds_raw);

    const int tid = threadIdx.x;
    const int wave = tid >> 6;
    const int lane = tid & 63;
    const int quad = lane >> 4;
    const int l15 = lane & 15;
    const int wm = wave >> 2;  // 0..1 : rows [wm*128, +128)
    const int wn = wave & 3;   // 0..3 : cols [wn*64, +64)

    // XCD-aware block swizzle (512 blocks, 8 XCDs, 64/XCD; then M-row-major within chunk)
    const int bswz = (blockIdx.x & 7) * 64 + (blockIdx.x >> 3);
    const int m0 = (bswz >> 4) * 256;  // 32 M-tiles
    const int n0 = (bswz & 15) * 256;  // 16 N-tiles

    // staging lane map: lane l writes phys LDS chunk (row r0+(l>>3), chunk l&7);
    // logical chunk = (l&7) ^ (l>>3)  (inverse of the read-side XOR swizzle; valid since
    // every staging r0 is a multiple of 8, so phys_row&7 == l>>3)
    const int stg_row = lane >> 3;
    const int stg_col = ((lane & 7) ^ stg_row) * 8;  // u16 units
    const u16* Ag = A + (size_t)(m0 + stg_row) * K_DIM + stg_col;
    const u16* Bg = Bt + (size_t)(n0 + stg_row) * K_DIM + stg_col;
    const int bw = (wave & 3) * 8 + (wave >> 2) * 64;  // B-issue row base per wave

    // ds_read swizzled column offsets: (ks*64 + quad*16) ^ ((l15&7)<<4)
    // (fragment base rows are multiples of 16, so read_row&7 == l15&7)
    const int xorv = (l15 & 7) << 4;
    const int ck0 = (quad * 16) ^ xorv;
    const int ck1 = (64 + quad * 16) ^ xorv;

    const char* asb0 = (const char*)&lds[0][0] + wm * 16384 + l15 * 128;
    const char* asb1 = asb0 + 32768;
    const char* bsb0 = (const char*)&lds[2][0] + wn * 8192 + l15 * 128;
    const char* bsb1 = bsb0 + 32768;

    bf16x8 a[4][2];
    bf16x8 b[4][2];
    f32x4 acc[8][4];
#pragma unroll
    for (int i = 0; i < 8; i++)
#pragma unroll
        for (int j = 0; j < 4; j++) acc[i][j] = (f32x4){0.f, 0.f, 0.f, 0.f};

    // ---- prologue: stage tile 0 in the loop's group order {A0,B0,B1}, {A1}
    STAGE_A(0, 0, 0);
    STAGE_B(0, 0, 0);
    STAGE_B(0, 0, 1);
    STAGE_A(0, 0, 1);

    // ---- main loop: 64 K-tiles, double-buffered. Last iteration re-stages tile (64&63)=0
    // into buf0 (dead but in-bounds; never read).
#pragma unroll 1
    for (int t = 0; t < 64; t += 2) {
        KTILE(asb0, bsb0, 1, t + 1);
        KTILE(asb1, bsb1, 0, (t + 2) & 63);
    }
    VMC(0);  // retire dangling dead-stage loads before LDS is released

    // ---- epilogue: C/D layout col = l15 (N), row = quad*4 + reg (M)  [m89/m91-verified]
    const float s_w = __uint_as_float(*mb) * (1.0f / 128.0f);
#pragma unroll
    for (int nj = 0; nj < 4; ++nj) {
        const int col = n0 + wn * 64 + nj * 16 + l15;
        const float bv = bias[col];
#pragma unroll
        for (int mi = 0; mi < 8; ++mi) {
            const int row = m0 + wm * 128 + mi * 16 + quad * 4;
            float* op = out + (size_t)row * N_DIM + col;
#pragma unroll
            for (int r = 0; r < 4; ++r) op[(size_t)r * N_DIM] = s_w * acc[mi][nj][r] + bv;
        }
    }
}

extern "C" void kernel_launch(void* const* d_in, const int* in_sizes, int n_in,
                              void* d_out, int out_size, void* d_ws, size_t ws_size,
                              hipStream_t stream) {
    const float* xb = (const float*)d_in[0];  // 8192 x 4096 fp32
    const float* W = (const float*)d_in[1];   // 4096 x 4096 fp32
    const float* b = (const float*)d_in[2];   // 4096 fp32
    float* out = (float*)d_out;               // 8192 x 4096 fp32

    // workspace layout: [0,4): maxabs bits | [256, 256+64M): xb bf16 | then W^T bf16 (32M)
    u32* mb = (u32*)d_ws;
    u16* xb_bf = (u16*)((char*)d_ws + 256);
    u16* wqt = (u16*)((char*)d_ws + 256 + (size_t)M_DIM * K_DIM * 2);

    hipMemsetAsync(d_ws, 0, 4, stream);  // ws is re-poisoned 0xAA before every call
    maxabs_kernel<<<1024, 256, 0, stream>>>(W, mb, (K_DIM * N_DIM) / 4);
    quant_transpose_kernel<<<dim3(N_DIM / 32, K_DIM / 32), dim3(32, 8), 0, stream>>>(W, wqt, mb);
    cast_bf16_kernel<<<4096, 256, 0, stream>>>(xb, xb_bf, (M_DIM * K_DIM) / 4);
    gemm_kernel<<<dim3(512), dim3(512), 131072, stream>>>(xb_bf, wqt, b, mb, out);
}

// Round 4
// 527.429 us; speedup vs baseline: 1.0584x; 1.0584x over previous
//
#include <hip/hip_runtime.h>
#include <hip/hip_bf16.h>
#include <stdint.h>

typedef unsigned short u16;
typedef unsigned int u32;
typedef __bf16 bf16x8 __attribute__((ext_vector_type(8)));
typedef float f32x4 __attribute__((ext_vector_type(4)));
typedef u16 u16x4 __attribute__((ext_vector_type(4)));
typedef u16 u16x8 __attribute__((ext_vector_type(8)));

typedef const __attribute__((address_space(1))) void* gas_ptr;
typedef __attribute__((address_space(3))) void* las_ptr;

#define M_DIM 8192
#define K_DIM 4096
#define N_DIM 4096

__device__ __forceinline__ u16 f32_to_bf16_rne(float f) {
    u32 u = __float_as_uint(f);
    u += 0x7FFFu + ((u >> 16) & 1u);
    return (u16)(u >> 16);
}

// ---- 1) fused: xb fp32->bf16 cast (blocks 0..4095) + max|W| reduction (blocks 4096..5119).
// Both parts are pure streams with no mutual dependency; fusing removes one launch gap and
// overlaps their HBM traffic. Math/indexing identical to the previous separate kernels ->
// bitwise-identical outputs.
#define CAST_BLOCKS 4096
#define MAX_BLOCKS 1024
__global__ void cast_maxabs_kernel(const float* __restrict__ x, u16* __restrict__ y,
                                   const float* __restrict__ W, u32* __restrict__ out) {
    const int bid = blockIdx.x;
    if (bid < CAST_BLOCKS) {
        // cast: (M*K)/4 float4 over 4096 blocks x 256 thr (8 iters/thread)
        const int n4 = (M_DIM * K_DIM) / 4;
        int idx = bid * 256 + threadIdx.x;
        const int stride = CAST_BLOCKS * 256;
        const float4* x4 = (const float4*)x;
        u16x4* y4 = (u16x4*)y;
        for (int i = idx; i < n4; i += stride) {
            float4 v = x4[i];
            u16x4 o;
            o.x = f32_to_bf16_rne(v.x);
            o.y = f32_to_bf16_rne(v.y);
            o.z = f32_to_bf16_rne(v.z);
            o.w = f32_to_bf16_rne(v.w);
            y4[i] = o;
        }
    } else {
        // maxabs: (K*N)/4 float4 over 1024 blocks x 256 thr (16 iters/thread)
        const int n4 = (K_DIM * N_DIM) / 4;
        int idx = (bid - CAST_BLOCKS) * 256 + threadIdx.x;
        const int stride = MAX_BLOCKS * 256;
        const float4* W4 = (const float4*)W;
        float m = 0.0f;
        for (int i = idx; i < n4; i += stride) {
            float4 v = W4[i];
            m = fmaxf(m, fmaxf(fmaxf(fabsf(v.x), fabsf(v.y)), fmaxf(fabsf(v.z), fabsf(v.w))));
        }
#pragma unroll
        for (int off = 32; off > 0; off >>= 1)
            m = fmaxf(m, __shfl_down(m, off));
        if ((threadIdx.x & 63) == 0)
            atomicMax(out, __float_as_uint(m));
    }
}

// ---- 2) quantize W (K x N, fp32) -> bf16 W^T (N x K). w_q integer in [-127,127]: exact in bf16.
// Coalescing-fixed rewrite: 64x64 tile/block; loads are 256B-contiguous row segments
// (16 lanes x float4), stores are 128B-contiguous u16x8 segments along K (8 lanes x 16B).
// LDS tile [k][n] with 73-u16 row stride (146B): load-phase writes are 8B-contiguous
// (conflict-free); store-phase column gather spreads across banks (146B = 36.5 dwords,
// 8-row step = 292 dwords = 4 mod 32 -> the 8 k-groups land on distinct bank quads).
// Same quantize math + same output addresses as before -> bitwise-identical W^T.
__device__ __forceinline__ u16 quantize_bf16(float v, float s_inv) {
    float q = rintf(v * s_inv);  // rintf = round-half-even (matches jnp.round)
    q = fminf(fmaxf(q, -127.0f), 127.0f);
    return (u16)(__float_as_uint(q) >> 16);  // truncation exact for small ints
}

__global__ void quant_transpose_kernel(const float* __restrict__ W, u16* __restrict__ Wt,
                                       const u32* __restrict__ mb) {
    __shared__ u16 tile[64][73];  // [k_local][n_local], padded row
    const float s_inv = 128.0f / __uint_as_float(*mb);  // 1/s_w, s_w = 2*max/256 = max/128
    const int n0 = blockIdx.x * 64;
    const int k0 = blockIdx.y * 64;
    const int t = threadIdx.x;  // 256 threads

    // load: 64 k-rows x 64 n; thread t handles row (p*16 + t/16), n-offset (t%16)*4
    const int lr = t >> 4;
    const int lc = (t & 15) * 4;
#pragma unroll
    for (int p = 0; p < 4; ++p) {
        const int k = k0 + p * 16 + lr;
        const float4 v = *(const float4*)&W[(size_t)k * N_DIM + n0 + lc];
        u16* d = &tile[p * 16 + lr][lc];
        d[0] = quantize_bf16(v.x, s_inv);
        d[1] = quantize_bf16(v.y, s_inv);
        d[2] = quantize_bf16(v.z, s_inv);
        d[3] = quantize_bf16(v.w, s_inv);
    }
    __syncthreads();

    // store: 64 n-rows x 64 k; thread t handles n-row (p*32 + t/8), k-offset (t%8)*8
    const int sr = t >> 3;
    const int sc = (t & 7) * 8;
#pragma unroll
    for (int p = 0; p < 2; ++p) {
        const int n = p * 32 + sr;
        u16x8 o;
#pragma unroll
        for (int j = 0; j < 8; ++j) o[j] = tile[sc + j][n];
        *(u16x8*)&Wt[(size_t)(n0 + n) * K_DIM + k0 + sc] = o;
    }
}

// ---- 3) GEMM: out[M][N] = s_w * (A[M][K] @ Bt[N][K]^T) + bias
// 256x256 tile, BK=64, 8 waves (2M x 4N), double-buffered LDS, counted vmcnt, XOR swizzle
// (bank conflicts measured 0). UNCHANGED from round 3 (proven, bitwise-stable output).

#define BAR() __builtin_amdgcn_s_barrier()
#define SCB() __builtin_amdgcn_sched_barrier(0)
#define VMC(N) asm volatile("s_waitcnt vmcnt(" #N ")" ::: "memory")
#define PRIO1() __builtin_amdgcn_s_setprio(1)
#define PRIO0() __builtin_amdgcn_s_setprio(0)

// ds-read A fragments for m-half MH: a[i][ks], rows wm*128 + MH*64 + i*16 + l15
#define DS_A(ABASE, MH)                                            \
    do {                                                           \
        _Pragma("unroll") for (int i_ = 0; i_ < 4; ++i_) {         \
            const char* p_ = (ABASE) + ((MH)*64 + i_ * 16) * 128;  \
            a[i_][0] = *(const bf16x8*)(p_ + ck0);                 \
            a[i_][1] = *(const bf16x8*)(p_ + ck1);                 \
        }                                                          \
    } while (0)

// ds-read B fragments for n-half NH: b[NH*2+j][ks], rows wn*64 + NH*32 + j*16 + l15
#define DS_B(BBASE, NH)                                            \
    do {                                                           \
        _Pragma("unroll") for (int j_ = 0; j_ < 2; ++j_) {         \
            const char* p_ = (BBASE) + ((NH)*32 + j_ * 16) * 128;  \
            b[(NH)*2 + j_][0] = *(const bf16x8*)(p_ + ck0);        \
            b[(NH)*2 + j_][1] = *(const bf16x8*)(p_ + ck1);        \
        }                                                          \
    } while (0)

// 16 MFMAs: one C-quadrant (MH, NH) over full K=64 of the current tile
#define MM(MH, NH)                                                                            \
    do {                                                                                      \
        _Pragma("unroll") for (int i_ = 0; i_ < 4; ++i_) {                                    \
            _Pragma("unroll") for (int j_ = 0; j_ < 2; ++j_) {                                \
                f32x4& c_ = acc[(MH)*4 + i_][(NH)*2 + j_];                                    \
                c_ = __builtin_amdgcn_mfma_f32_16x16x32_bf16(a[i_][0], b[(NH)*2 + j_][0], c_, \
                                                             0, 0, 0);                        \
                c_ = __builtin_amdgcn_mfma_f32_16x16x32_bf16(a[i_][1], b[(NH)*2 + j_][1], c_, \
                                                             0, 0, 0);                        \
            }                                                                                 \
        }                                                                                     \
    } while (0)

// stage A half-tile HALF of k-tile T into buffer BUF (2 x global_load_lds)
#define STAGE_A(BUF, T, HALF)                                                                 \
    do {                                                                                      \
        const int r0_ = wave * 8 + (HALF)*64;                                                 \
        const u16* s_ = Ag + (size_t)r0_ * K_DIM + (T)*64;                                    \
        __builtin_amdgcn_global_load_lds((gas_ptr)s_, (las_ptr)&lds[BUF][r0_ * 64], 16, 0,    \
                                         0);                                                  \
        __builtin_amdgcn_global_load_lds((gas_ptr)(s_ + (size_t)128 * K_DIM),                 \
                                         (las_ptr)&lds[BUF][(r0_ + 128) * 64], 16, 0, 0);     \
    } while (0)

// stage B half-tile
#define STAGE_B(BUF, T, HALF)                                                                  \
    do {                                                                                       \
        const int r0_ = bw + (HALF)*32;                                                        \
        const u16* s_ = Bg + (size_t)r0_ * K_DIM + (T)*64;                                     \
        __builtin_amdgcn_global_load_lds((gas_ptr)s_, (las_ptr)&lds[2 + (BUF)][r0_ * 64], 16,  \
                                         0, 0);                                                \
        __builtin_amdgcn_global_load_lds((gas_ptr)(s_ + (size_t)128 * K_DIM),                  \
                                         (las_ptr)&lds[2 + (BUF)][(r0_ + 128) * 64], 16, 0,    \
                                         0);                                                   \
    } while (0)

// One K-tile, 2 barriers; stage k-tile TS into OBUF. vmcnt FIFO: 6-group {A0,B0,B1} then
// 2-group {A1} per tile; VMC(2) waits current tile's 6-group, VMC(6) waits its A1.
#define KTILE(ABASE, BBASE, OBUF, TS)  \
    do {                               \
        VMC(2);                        \
        BAR();                         \
        SCB();                         \
        STAGE_A(OBUF, TS, 0);          \
        STAGE_B(OBUF, TS, 0);          \
        STAGE_B(OBUF, TS, 1);          \
        DS_A(ABASE, 0);                \
        DS_B(BBASE, 0);                \
        DS_B(BBASE, 1);                \
        SCB();                         \
        PRIO1();                       \
        MM(0, 0);                      \
        MM(0, 1);                      \
        PRIO0();                       \
        VMC(6);                        \
        BAR();                         \
        SCB();                         \
        STAGE_A(OBUF, TS, 1);          \
        DS_A(ABASE, 1);                \
        SCB();                         \
        PRIO1();                       \
        MM(1, 0);                      \
        MM(1, 1);                      \
        PRIO0();                       \
    } while (0)

__global__ __launch_bounds__(512, 2) void gemm_kernel(const u16* __restrict__ A,
                                                      const u16* __restrict__ Bt,
                                                      const float* __restrict__ bias,
                                                      const u32* __restrict__ mb,
                                                      float* __restrict__ out) {
    extern __shared__ u16 lds_raw[];  // 128 KiB dynamic: A buf0, A buf1, B buf0, B buf1
    u16(*lds)[256 * 64] = reinterpret_cast<u16(*)[256 * 64]>(lds_raw);

    const int tid = threadIdx.x;
    const int wave = tid >> 6;
    const int lane = tid & 63;
    const int quad = lane >> 4;
    const int l15 = lane & 15;
    const int wm = wave >> 2;  // 0..1 : rows [wm*128, +128)
    const int wn = wave & 3;   // 0..3 : cols [wn*64, +64)

    // XCD-aware block swizzle (512 blocks, 8 XCDs, 64/XCD; then M-row-major within chunk)
    const int bswz = (blockIdx.x & 7) * 64 + (blockIdx.x >> 3);
    const int m0 = (bswz >> 4) * 256;  // 32 M-tiles
    const int n0 = (bswz & 15) * 256;  // 16 N-tiles

    // staging lane map: lane l writes phys LDS chunk (row r0+(l>>3), chunk l&7);
    // logical chunk = (l&7) ^ (l>>3)  (inverse of the read-side XOR swizzle)
    const int stg_row = lane >> 3;
    const int stg_col = ((lane & 7) ^ stg_row) * 8;  // u16 units
    const u16* Ag = A + (size_t)(m0 + stg_row) * K_DIM + stg_col;
    const u16* Bg = Bt + (size_t)(n0 + stg_row) * K_DIM + stg_col;
    const int bw = (wave & 3) * 8 + (wave >> 2) * 64;  // B-issue row base per wave

    // ds_read swizzled column offsets: (ks*64 + quad*16) ^ ((l15&7)<<4)
    const int xorv = (l15 & 7) << 4;
    const int ck0 = (quad * 16) ^ xorv;
    const int ck1 = (64 + quad * 16) ^ xorv;

    const char* asb0 = (const char*)&lds[0][0] + wm * 16384 + l15 * 128;
    const char* asb1 = asb0 + 32768;
    const char* bsb0 = (const char*)&lds[2][0] + wn * 8192 + l15 * 128;
    const char* bsb1 = bsb0 + 32768;

    bf16x8 a[4][2];
    bf16x8 b[4][2];
    f32x4 acc[8][4];
#pragma unroll
    for (int i = 0; i < 8; i++)
#pragma unroll
        for (int j = 0; j < 4; j++) acc[i][j] = (f32x4){0.f, 0.f, 0.f, 0.f};

    // ---- prologue: stage tile 0 in the loop's group order {A0,B0,B1}, {A1}
    STAGE_A(0, 0, 0);
    STAGE_B(0, 0, 0);
    STAGE_B(0, 0, 1);
    STAGE_A(0, 0, 1);

    // ---- main loop: 64 K-tiles, double-buffered. Last iteration re-stages tile 0 (dead).
#pragma unroll 1
    for (int t = 0; t < 64; t += 2) {
        KTILE(asb0, bsb0, 1, t + 1);
        KTILE(asb1, bsb1, 0, (t + 2) & 63);
    }
    VMC(0);  // retire dangling dead-stage loads before LDS is released

    // ---- epilogue: C/D layout col = l15 (N), row = quad*4 + reg (M)  [m89/m91-verified]
    const float s_w = __uint_as_float(*mb) * (1.0f / 128.0f);
#pragma unroll
    for (int nj = 0; nj < 4; ++nj) {
        const int col = n0 + wn * 64 + nj * 16 + l15;
        const float bv = bias[col];
#pragma unroll
        for (int mi = 0; mi < 8; ++mi) {
            const int row = m0 + wm * 128 + mi * 16 + quad * 4;
            float* op = out + (size_t)row * N_DIM + col;
#pragma unroll
            for (int r = 0; r < 4; ++r) op[(size_t)r * N_DIM] = s_w * acc[mi][nj][r] + bv;
        }
    }
}

extern "C" void kernel_launch(void* const* d_in, const int* in_sizes, int n_in,
                              void* d_out, int out_size, void* d_ws, size_t ws_size,
                              hipStream_t stream) {
    const float* xb = (const float*)d_in[0];  // 8192 x 4096 fp32
    const float* W = (const float*)d_in[1];   // 4096 x 4096 fp32
    const float* b = (const float*)d_in[2];   // 4096 fp32
    float* out = (float*)d_out;               // 8192 x 4096 fp32

    // workspace layout: [0,4): maxabs bits | [256, 256+64M): xb bf16 | then W^T bf16 (32M)
    u32* mb = (u32*)d_ws;
    u16* xb_bf = (u16*)((char*)d_ws + 256);
    u16* wqt = (u16*)((char*)d_ws + 256 + (size_t)M_DIM * K_DIM * 2);

    hipMemsetAsync(d_ws, 0, 4, stream);  // ws is re-poisoned 0xAA before every call
    cast_maxabs_kernel<<<CAST_BLOCKS + MAX_BLOCKS, 256, 0, stream>>>(xb, xb_bf, W, mb);
    quant_transpose_kernel<<<dim3(N_DIM / 64, K_DIM / 64), 256, 0, stream>>>(W, wqt, mb);
    gemm_kernel<<<dim3(512), dim3(512), 131072, stream>>>(xb_bf, wqt, b, mb, out);
}